// Round 6
// baseline (431.287 us; speedup 1.0000x reference)
//
#include <hip/hip_runtime.h>
#include <math.h>

// MultiHeadAttentionMemory: B=256, F=4096, M=4096 memories.
// seq_len==1 => attention==identity => o = (z@Wv+bv)@Wo+bo  (Wq/Wk dead).
// Split-bf16 (bf16x3: ah*bh + ah*bl + al*bh) MFMA for the 3 precision-
// sensitive GEMMs; plain bf16 MFMA for z_hat = w@mem.
// GEMM tiling for TLP: BM=128 x BN=64, 4 waves (2m x 2n of 64x32),
// grid (64,2,8) = 1024 blocks = 4 blocks/CU = 4 waves/SIMD.
// B staged via global_load_lds, double-buffered; A register-prefetched.
#define MB 256
#define FF 4096

typedef __attribute__((ext_vector_type(8))) short short8v;
typedef __attribute__((ext_vector_type(4))) short short4v;
typedef __attribute__((ext_vector_type(16))) float f32x16;

__device__ __forceinline__ unsigned short bf16_rne(float f) {
    unsigned u = __builtin_bit_cast(unsigned, f);
    u += 0x7fffu + ((u >> 16) & 1u);
    return (unsigned short)(u >> 16);
}
__device__ __forceinline__ float bf16_f(unsigned short h) {
    unsigned u = ((unsigned)h) << 16;
    return __builtin_bit_cast(float, u);
}

// async global->LDS, 16B per lane; lds ptr must be wave-uniform.
#define GLL16(g, l)                                                          \
    __builtin_amdgcn_global_load_lds(                                        \
        (const __attribute__((address_space(1))) unsigned int*)(g),          \
        (__attribute__((address_space(3))) unsigned int*)(l), 16, 0, 0)

// ---------------- reductions ----------------
__device__ __forceinline__ float block_reduce_sum(float v, float* red) {
    const int tid = threadIdx.x;
    red[tid] = v; __syncthreads();
    for (int s = 128; s > 0; s >>= 1) {
        if (tid < s) red[tid] += red[tid + s];
        __syncthreads();
    }
    float r = red[0]; __syncthreads();
    return r;
}
__device__ __forceinline__ float block_reduce_max(float v, float* red) {
    const int tid = threadIdx.x;
    red[tid] = v; __syncthreads();
    for (int s = 128; s > 0; s >>= 1) {
        if (tid < s) red[tid] = fmaxf(red[tid], red[tid + s]);
        __syncthreads();
    }
    float r = red[0]; __syncthreads();
    return r;
}

// dst[row] = max(||src[row,:]||, 1e-8)
__global__ __launch_bounds__(256) void rownorm_kernel(
    const float* __restrict__ src, float* __restrict__ dst, int ncols)
{
    __shared__ float red[256];
    const int row = blockIdx.x, tid = threadIdx.x;
    const float4* p = (const float4*)(src + (size_t)row * ncols);
    float s = 0.f;
    for (int i = tid; i < ncols / 4; i += 256) {
        float4 v = p[i];
        s += v.x * v.x + v.y * v.y + v.z * v.z + v.w * v.w;
    }
    float tot = block_reduce_sum(s, red);
    if (tid == 0) dst[row] = fmaxf(sqrtf(tot), 1e-8f);
}

// ---------------- fp32 -> bf16 hi/lo split (straight) ----------------
__global__ __launch_bounds__(256) void split_plain(
    const float* __restrict__ src, unsigned short* __restrict__ hi,
    unsigned short* __restrict__ lo)
{
    const size_t i4 = (size_t)blockIdx.x * 256 + threadIdx.x;
    const float4 v = *(const float4*)(src + i4 * 4);
    unsigned short h0 = bf16_rne(v.x), h1 = bf16_rne(v.y), h2 = bf16_rne(v.z), h3 = bf16_rne(v.w);
    short4v hv = { (short)h0, (short)h1, (short)h2, (short)h3 };
    *(short4v*)(hi + i4 * 4) = hv;
    short4v lv = { (short)bf16_rne(v.x - bf16_f(h0)), (short)bf16_rne(v.y - bf16_f(h1)),
                   (short)bf16_rne(v.z - bf16_f(h2)), (short)bf16_rne(v.w - bf16_f(h3)) };
    *(short4v*)(lo + i4 * 4) = lv;
}

// ---------------- mem: fused split + rownorm (one 64MB pass) ----------------
__global__ __launch_bounds__(256) void split_norm_mem(
    const float* __restrict__ src, unsigned short* __restrict__ hi,
    unsigned short* __restrict__ lo, float* __restrict__ nrm)
{
    __shared__ float red[256];
    const int row = blockIdx.x, tid = threadIdx.x;
    const float4* p = (const float4*)(src + (size_t)row * FF);
    float s = 0.f;
    for (int i = tid; i < FF / 4; i += 256) {
        float4 v = p[i];
        s += v.x * v.x + v.y * v.y + v.z * v.z + v.w * v.w;
        unsigned short h0 = bf16_rne(v.x), h1 = bf16_rne(v.y), h2 = bf16_rne(v.z), h3 = bf16_rne(v.w);
        const size_t ob = (size_t)row * FF + i * 4;
        short4v hv = { (short)h0, (short)h1, (short)h2, (short)h3 };
        *(short4v*)(hi + ob) = hv;
        short4v lv = { (short)bf16_rne(v.x - bf16_f(h0)), (short)bf16_rne(v.y - bf16_f(h1)),
                       (short)bf16_rne(v.z - bf16_f(h2)), (short)bf16_rne(v.w - bf16_f(h3)) };
        *(short4v*)(lo + ob) = lv;
    }
    float tot = block_reduce_sum(s, red);
    if (tid == 0) nrm[row] = fmaxf(sqrtf(tot), 1e-8f);
}

// ---------------- transpose + split: src[4096][4096] f32 -> dstT[n][k] bf16 ----------------
template <int WRITE_LO>
__global__ __launch_bounds__(256) void transpose_split(
    const float* __restrict__ src, unsigned short* __restrict__ hi,
    unsigned short* __restrict__ lo)
{
    __shared__ float tile[32][33];
    const int bj = blockIdx.x;  // col block of src (= out row block)
    const int bi = blockIdx.y;  // row block of src (= out col block)
    const int t = threadIdx.x;
    const int ty = t >> 3, tx4 = (t & 7) << 2;
    const float4 v = *(const float4*)(src + (size_t)(bi * 32 + ty) * FF + bj * 32 + tx4);
    tile[ty][tx4 + 0] = v.x; tile[ty][tx4 + 1] = v.y;
    tile[ty][tx4 + 2] = v.z; tile[ty][tx4 + 3] = v.w;
    __syncthreads();
    float o0 = tile[tx4 + 0][ty], o1 = tile[tx4 + 1][ty];
    float o2 = tile[tx4 + 2][ty], o3 = tile[tx4 + 3][ty];
    unsigned short h0 = bf16_rne(o0), h1 = bf16_rne(o1), h2 = bf16_rne(o2), h3 = bf16_rne(o3);
    const size_t ob = (size_t)(bj * 32 + ty) * FF + bi * 32 + tx4;
    short4v hv = { (short)h0, (short)h1, (short)h2, (short)h3 };
    *(short4v*)(hi + ob) = hv;
    if constexpr (WRITE_LO) {
        short4v lv = { (short)bf16_rne(o0 - bf16_f(h0)), (short)bf16_rne(o1 - bf16_f(h1)),
                       (short)bf16_rne(o2 - bf16_f(h2)), (short)bf16_rne(o3 - bf16_f(h3)) };
        *(short4v*)(lo + ob) = lv;
    }
}

// ---------------- MFMA GEMM, split-K, high-occupancy tiling ----------------
// C[256][4096] = A[256][4096] @ BT^T  (BT stored [n][k] bf16 planes).
// grid (64, 2, 8); block 256 = 4 waves (2m x 2n), block tile 128x64,
// wave tile 64x32 (2 m-subtiles of 32), BK=32, K-chunk 512 (16 tiles).
// B hi/lo staged via global_load_lds into 2 LDS buffers (8KB each, split);
// A hi/lo register-direct, 1 tile ahead. 4 blocks/CU -> 4 waves/SIMD TLP.
template <int SPLIT>
__global__ __launch_bounds__(256, 4) void gemm_sk(
    const unsigned short* __restrict__ Ah, const unsigned short* __restrict__ Al,
    const unsigned short* __restrict__ Bh, const unsigned short* __restrict__ Bl,
    float* __restrict__ part)
{
    constexpr int PLANES = SPLIT ? 2 : 1;
    constexpr int BUFBYTES = PLANES * 4096;           // bytes per LDS buffer
    __shared__ unsigned short Bs[2 * PLANES * 2048];  // 2 buffers

    const int tid = threadIdx.x;
    const int lane = tid & 63, w = tid >> 6;
    const int wr = w >> 1, wc = w & 1;
    const int m0 = blockIdx.y * 128 + wr * 64;
    const int bn0 = blockIdx.x * 64;
    const int k0 = blockIdx.z * 512;
    const int l31 = lane & 31;

    // ---- staging (B): slot tid -> n = tid&63, k8 = tid>>6; LDS byte = tid*16
    const size_t brow_off = (size_t)(bn0 + (tid & 63)) * FF + k0 + (tid >> 6) * 8;
    const unsigned short* bsh = Bh + brow_off;
    const unsigned short* bsl = SPLIT ? (Bl + brow_off) : bsh;
    char* const lwave = (char*)Bs + (tid >> 6) * 1024;  // wave-uniform base

#define STAGE(BUF_, T_)                                                       \
    {                                                                         \
        GLL16(bsh + (T_) * 32, lwave + (BUF_) * BUFBYTES + 0);                \
        if constexpr (SPLIT) {                                                \
            GLL16(bsl + (T_) * 32, lwave + (BUF_) * BUFBYTES + 4096);         \
        }                                                                     \
    }

    // ---- B fragment reads: byte = ((ks*2 + (lane>>5))*64 + wc*32 + l31)*16
    //      -> per instruction: two contiguous 512B runs, conflict-free.
    const char* const fragbase =
        (const char*)Bs + (((lane >> 5) * 64) + wc * 32 + l31) * 16;
#define BFRAG(BUF_, P_, KS_)                                                  \
    (*(const short8v*)(fragbase + (BUF_) * BUFBYTES + (P_) * 4096 + (KS_) * 2048))

    // ---- A pointers (register-direct)
    const size_t arow = (size_t)(m0 + l31) * FF + k0 + (lane >> 5) * 8;
    const unsigned short* a0h = Ah + arow;
    const unsigned short* a1h = a0h + (size_t)32 * FF;
    const unsigned short* a0l = SPLIT ? (Al + arow) : a0h;
    const unsigned short* a1l = a0l + (size_t)32 * FF;

    short8v cA_0h0, cA_0h1, cA_1h0, cA_1h1, cA_0l0, cA_0l1, cA_1l0, cA_1l1;
    short8v nA_0h0, nA_0h1, nA_1h0, nA_1h1, nA_0l0, nA_0l1, nA_1l0, nA_1l1;

#define LOADA(SET, T_)                                                        \
    {                                                                         \
        const int o_ = (T_) * 32;                                             \
        SET##_0h0 = *(const short8v*)(a0h + o_);                              \
        SET##_0h1 = *(const short8v*)(a0h + o_ + 16);                         \
        SET##_1h0 = *(const short8v*)(a1h + o_);                              \
        SET##_1h1 = *(const short8v*)(a1h + o_ + 16);                         \
        if constexpr (SPLIT) {                                                \
            SET##_0l0 = *(const short8v*)(a0l + o_);                          \
            SET##_0l1 = *(const short8v*)(a0l + o_ + 16);                     \
            SET##_1l0 = *(const short8v*)(a1l + o_);                          \
            SET##_1l1 = *(const short8v*)(a1l + o_ + 16);                     \
        }                                                                     \
    }

    f32x16 acc0 = 0.0f, acc1 = 0.0f;

#define MFMA(A_, B_, C_) C_ = __builtin_amdgcn_mfma_f32_32x32x16_bf16(A_, B_, C_, 0, 0, 0)
#define MMKS(SET, BUF_, KS_)                                                  \
    {                                                                         \
        short8v bh = BFRAG(BUF_, 0, KS_);                                     \
        MFMA(SET##_0h##KS_, bh, acc0); MFMA(SET##_1h##KS_, bh, acc1);         \
        if constexpr (SPLIT) {                                                \
            short8v bl = BFRAG(BUF_, 1, KS_);                                 \
            MFMA(SET##_0h##KS_, bl, acc0); MFMA(SET##_1h##KS_, bl, acc1);     \
            MFMA(SET##_0l##KS_, bh, acc0); MFMA(SET##_1l##KS_, bh, acc1);     \
        }                                                                     \
    }

    // prologue: tile 0 -> buf0, A(0) -> cA
    STAGE(0, 0)
    LOADA(cA, 0)
    __syncthreads();

#pragma unroll
    for (int tp = 0; tp < 8; ++tp) {
        const int t = tp * 2;
        // even tile t (buf0, cA); prefetch t+1
        STAGE(1, t + 1)
        LOADA(nA, t + 1)
        __builtin_amdgcn_s_setprio(1);
        MMKS(cA, 0, 0)
        MMKS(cA, 0, 1)
        __builtin_amdgcn_s_setprio(0);
        __syncthreads();
        // odd tile t+1 (buf1, nA); prefetch t+2
        if (tp < 7) { STAGE(0, t + 2) LOADA(cA, t + 2) }
        __builtin_amdgcn_s_setprio(1);
        MMKS(nA, 1, 0)
        MMKS(nA, 1, 1)
        __builtin_amdgcn_s_setprio(0);
        __syncthreads();
    }
#undef STAGE
#undef BFRAG
#undef LOADA
#undef MFMA
#undef MMKS

    float* pp = part + (size_t)blockIdx.z * (MB * FF);
    const int rbase = m0 + 4 * (lane >> 5);
    const int c0 = bn0 + wc * 32 + l31;
#pragma unroll
    for (int r = 0; r < 16; ++r) {
        const int row0 = rbase + (r & 3) + 8 * (r >> 2);
        float* rp0 = pp + (size_t)row0 * FF + c0;
        rp0[0] = acc0[r];
        float* rp1 = rp0 + (size_t)32 * FF;
        rp1[0] = acc1[r];
    }
}

// ---------------- split-K reduce + epilogue ----------------
// MODE 0: +bias -> hi/lo planes.  MODE 1: +bias -> hi/lo + f32.
// MODE 2: /(zn*mn) -> f32.        MODE 3: plain -> f32.
template <int MODE>
__global__ __launch_bounds__(256) void reduce_k(
    const float* __restrict__ part, const float* __restrict__ bias,
    const float* __restrict__ zn, const float* __restrict__ mn,
    unsigned short* __restrict__ hi, unsigned short* __restrict__ lo,
    float* __restrict__ fout)
{
    const size_t idx4 = (size_t)blockIdx.x * 256 + threadIdx.x;
    const size_t base = idx4 * 4;
    float s0 = 0.f, s1 = 0.f, s2 = 0.f, s3 = 0.f;
#pragma unroll
    for (int c = 0; c < 8; ++c) {
        const float4 p = *(const float4*)(part + (size_t)c * (MB * FF) + base);
        s0 += p.x; s1 += p.y; s2 += p.z; s3 += p.w;
    }
    const int col = (int)(base & 4095);
    const int row = (int)(base >> 12);
    if constexpr (MODE == 0 || MODE == 1) {
        s0 += bias[col]; s1 += bias[col + 1]; s2 += bias[col + 2]; s3 += bias[col + 3];
        unsigned short h0 = bf16_rne(s0), h1 = bf16_rne(s1), h2 = bf16_rne(s2), h3 = bf16_rne(s3);
        short4v hv = { (short)h0, (short)h1, (short)h2, (short)h3 };
        *(short4v*)(hi + base) = hv;
        short4v lv = { (short)bf16_rne(s0 - bf16_f(h0)), (short)bf16_rne(s1 - bf16_f(h1)),
                       (short)bf16_rne(s2 - bf16_f(h2)), (short)bf16_rne(s3 - bf16_f(h3)) };
        *(short4v*)(lo + base) = lv;
        if constexpr (MODE == 1) {
            float4 o = { s0, s1, s2, s3 };
            *(float4*)(fout + base) = o;
        }
    } else if constexpr (MODE == 2) {
        const float zr = zn[row];
        float4 o = { s0 / (zr * mn[col]), s1 / (zr * mn[col + 1]),
                     s2 / (zr * mn[col + 2]), s3 / (zr * mn[col + 3]) };
        *(float4*)(fout + base) = o;
    } else {
        float4 o = { s0, s1, s2, s3 };
        *(float4*)(fout + base) = o;
    }
}

// ---------------- softmax + shrinkage + renorm + entropy ----------------
__global__ __launch_bounds__(256) void softmax_shrink_kernel(
    const float* __restrict__ logits, unsigned short* __restrict__ w_hi,
    float* __restrict__ rowent)
{
    constexpr float THRESH = 1.0f / 4096.0f;
    constexpr float EPS = 1e-12f;
    __shared__ float srow[4096];
    __shared__ float red[256];
    const int row = blockIdx.x, tid = threadIdx.x;
    const float4* p = (const float4*)(logits + (size_t)row * FF);
    for (int i = tid; i < FF / 4; i += 256) ((float4*)srow)[i] = p[i];
    __syncthreads();

    float m = -INFINITY;
    for (int i = tid; i < FF; i += 256) m = fmaxf(m, srow[i]);
    m = block_reduce_max(m, red);

    float s = 0.f;
    for (int i = tid; i < FF; i += 256) {
        float e = expf(srow[i] - m);
        srow[i] = e; s += e;
    }
    s = block_reduce_sum(s, red);
    const float inv = 1.0f / s;

    float s2 = 0.f;
    for (int i = tid; i < FF; i += 256) {
        float w = srow[i] * inv;
        float d = w - THRESH;
        float w2 = fmaxf(d, 0.f) * w / (fabsf(d) + EPS);
        srow[i] = w2; s2 += w2;
    }
    __syncthreads();
    s2 = block_reduce_sum(s2, red);
    const float inv2 = 1.0f / fmaxf(s2, EPS);

    float ent = 0.f;
    for (int i = tid; i < FF; i += 256) {
        float w3 = srow[i] * inv2;
        w_hi[(size_t)row * FF + i] = bf16_rne(w3);
        ent -= w3 * logf(w3 + EPS);
    }
    ent = block_reduce_sum(ent, red);
    if (tid == 0) rowent[row] = ent;
}

__global__ __launch_bounds__(256) void loss_kernel(
    const float* __restrict__ rowent, float* __restrict__ out)
{
    __shared__ float red[256];
    const int tid = threadIdx.x;
    float tot = block_reduce_sum(rowent[tid], red);
    if (tid == 0) out[0] = (tot / 256.0f) * 0.0002f;
}

extern "C" void kernel_launch(void* const* d_in, const int* in_sizes, int n_in,
                              void* d_out, int out_size, void* d_ws, size_t ws_size,
                              hipStream_t stream)
{
    // inputs: x, memory, Wq, bq, Wk, bk, Wv, bv, Wo, bo
    const float* x   = (const float*)d_in[0];
    const float* mem = (const float*)d_in[1];
    const float* Wv  = (const float*)d_in[6];
    const float* bv  = (const float*)d_in[7];
    const float* Wo  = (const float*)d_in[8];
    const float* bo  = (const float*)d_in[9];
    float* out = (float*)d_out;

    char* ws = (char*)d_ws;
    unsigned short* T_hi  = (unsigned short*)(ws);                 // 32 MB  (transposed weight hi)
    unsigned short* T_lo  = (unsigned short*)(ws + 33554432ull);   // 32 MB
    unsigned short* M_hi  = (unsigned short*)(ws + 67108864ull);   // 32 MB  (mem split, native)
    unsigned short* M_lo  = (unsigned short*)(ws + 100663296ull);  // 32 MB
    float*          part  = (float*)(ws + 134217728ull);           // 32 MB  (8 split-K partials)
    unsigned short* x_hi  = (unsigned short*)(ws + 167772160ull);  // 2 MB
    unsigned short* x_lo  = (unsigned short*)(ws + 169869312ull);
    unsigned short* v_hi  = (unsigned short*)(ws + 171966464ull);
    unsigned short* v_lo  = (unsigned short*)(ws + 174063616ull);
    unsigned short* o_hi  = (unsigned short*)(ws + 176160768ull);
    unsigned short* o_lo  = (unsigned short*)(ws + 178257920ull);
    float*          o_f32 = (float*)(ws + 180355072ull);           // 4 MB
    float*          logit = (float*)(ws + 184549376ull);           // 4 MB
    unsigned short* w_hi  = (unsigned short*)(ws + 188743680ull);  // 2 MB
    float*          zn    = (float*)(ws + 190840832ull);
    float*          mn    = zn + MB;
    float*          rowe  = mn + FF;

    const dim3 blk(256);
    const dim3 gG(64, 2, 8);      // gemm: N/64, M/128, split-K 8
    const dim3 gT(128, 128);      // transpose tiles
    const int gR = (MB * FF) / (4 * 256);  // 1024

    // prep
    split_plain<<<gR, blk, 0, stream>>>(x, x_hi, x_lo);
    split_norm_mem<<<FF, blk, 0, stream>>>(mem, M_hi, M_lo, mn);

    // v = z @ Wv + bv
    transpose_split<1><<<gT, blk, 0, stream>>>(Wv, T_hi, T_lo);
    gemm_sk<1><<<gG, blk, 0, stream>>>(x_hi, x_lo, T_hi, T_lo, part);
    reduce_k<0><<<gR, blk, 0, stream>>>(part, bv, nullptr, nullptr, v_hi, v_lo, nullptr);

    // o = v @ Wo + bo
    transpose_split<1><<<gT, blk, 0, stream>>>(Wo, T_hi, T_lo);
    gemm_sk<1><<<gG, blk, 0, stream>>>(v_hi, v_lo, T_hi, T_lo, part);
    reduce_k<1><<<gR, blk, 0, stream>>>(part, bo, nullptr, nullptr, o_hi, o_lo, o_f32);

    // logits = (o @ mem^T) / (zn x mn)   [mem native rows ARE B^T layout]
    rownorm_kernel<<<MB, blk, 0, stream>>>(o_f32, zn, FF);
    gemm_sk<1><<<gG, blk, 0, stream>>>(o_hi, o_lo, M_hi, M_lo, part);
    reduce_k<2><<<gR, blk, 0, stream>>>(part, nullptr, zn, mn, nullptr, nullptr, logit);

    // softmax/shrink/renorm/entropy -> w (bf16)
    softmax_shrink_kernel<<<MB, blk, 0, stream>>>(logit, w_hi, rowe);

    // z_hat = w @ mem  (plain bf16; needs mem^T planes)
    transpose_split<0><<<gT, blk, 0, stream>>>(mem, T_hi, nullptr);
    gemm_sk<0><<<gG, blk, 0, stream>>>(w_hi, nullptr, T_hi, nullptr, part);
    reduce_k<3><<<gR, blk, 0, stream>>>(part, nullptr, nullptr, nullptr, nullptr, nullptr, out);

    loss_kernel<<<1, blk, 0, stream>>>(rowe, out + (size_t)MB * FF);
}

// Round 7
// 250.929 us; speedup vs baseline: 1.7188x; 1.7188x over previous
//
#include <hip/hip_runtime.h>
#include <math.h>

// MultiHeadAttentionMemory: B=256, F=4096, M=4096 memories.
// seq_len==1 => attention==identity => o = (z@Wv+bv)@Wo+bo  (Wq/Wk dead).
// Split-bf16 (bf16x3) MFMA for the 3 precision-sensitive GEMMs; plain bf16
// for z_hat = w@mem. R7: BM=256 8-wave blocks (no B duplication); transpose+
// split folded into GEMM B-staging (reg-stage fp32 [k][n] -> split -> blocked
// LDS). No separate weight transpose passes.
#define MB 256
#define FF 4096

typedef __attribute__((ext_vector_type(8))) short short8v;
typedef __attribute__((ext_vector_type(4))) short short4v;
typedef __attribute__((ext_vector_type(16))) float f32x16;

__device__ __forceinline__ unsigned short bf16_rne(float f) {
    unsigned u = __builtin_bit_cast(unsigned, f);
    u += 0x7fffu + ((u >> 16) & 1u);
    return (unsigned short)(u >> 16);
}
__device__ __forceinline__ float bf16_f(unsigned short h) {
    unsigned u = ((unsigned)h) << 16;
    return __builtin_bit_cast(float, u);
}

// async global->LDS, 16B per lane; lds ptr must be wave-uniform.
#define GLL16(g, l)                                                          \
    __builtin_amdgcn_global_load_lds(                                        \
        (const __attribute__((address_space(1))) unsigned int*)(g),          \
        (__attribute__((address_space(3))) unsigned int*)(l), 16, 0, 0)

// ---------------- reductions ----------------
__device__ __forceinline__ float block_reduce_sum(float v, float* red) {
    const int tid = threadIdx.x;
    red[tid] = v; __syncthreads();
    for (int s = 128; s > 0; s >>= 1) {
        if (tid < s) red[tid] += red[tid + s];
        __syncthreads();
    }
    float r = red[0]; __syncthreads();
    return r;
}
__device__ __forceinline__ float block_reduce_max(float v, float* red) {
    const int tid = threadIdx.x;
    red[tid] = v; __syncthreads();
    for (int s = 128; s > 0; s >>= 1) {
        if (tid < s) red[tid] = fmaxf(red[tid], red[tid + s]);
        __syncthreads();
    }
    float r = red[0]; __syncthreads();
    return r;
}

// dst[row] = max(||src[row,:]||, 1e-8)
__global__ __launch_bounds__(256) void rownorm_kernel(
    const float* __restrict__ src, float* __restrict__ dst, int ncols)
{
    __shared__ float red[256];
    const int row = blockIdx.x, tid = threadIdx.x;
    const float4* p = (const float4*)(src + (size_t)row * ncols);
    float s = 0.f;
    for (int i = tid; i < ncols / 4; i += 256) {
        float4 v = p[i];
        s += v.x * v.x + v.y * v.y + v.z * v.z + v.w * v.w;
    }
    float tot = block_reduce_sum(s, red);
    if (tid == 0) dst[row] = fmaxf(sqrtf(tot), 1e-8f);
}

// ---------------- fp32 -> bf16 hi/lo split (straight) ----------------
__global__ __launch_bounds__(256) void split_plain(
    const float* __restrict__ src, unsigned short* __restrict__ hi,
    unsigned short* __restrict__ lo)
{
    const size_t i4 = (size_t)blockIdx.x * 256 + threadIdx.x;
    const float4 v = *(const float4*)(src + i4 * 4);
    unsigned short h0 = bf16_rne(v.x), h1 = bf16_rne(v.y), h2 = bf16_rne(v.z), h3 = bf16_rne(v.w);
    short4v hv = { (short)h0, (short)h1, (short)h2, (short)h3 };
    *(short4v*)(hi + i4 * 4) = hv;
    short4v lv = { (short)bf16_rne(v.x - bf16_f(h0)), (short)bf16_rne(v.y - bf16_f(h1)),
                   (short)bf16_rne(v.z - bf16_f(h2)), (short)bf16_rne(v.w - bf16_f(h3)) };
    *(short4v*)(lo + i4 * 4) = lv;
}

// ---------------- mem: fused split + rownorm (one 64MB pass) ----------------
__global__ __launch_bounds__(256) void split_norm_mem(
    const float* __restrict__ src, unsigned short* __restrict__ hi,
    unsigned short* __restrict__ lo, float* __restrict__ nrm)
{
    __shared__ float red[256];
    const int row = blockIdx.x, tid = threadIdx.x;
    const float4* p = (const float4*)(src + (size_t)row * FF);
    float s = 0.f;
    for (int i = tid; i < FF / 4; i += 256) {
        float4 v = p[i];
        s += v.x * v.x + v.y * v.y + v.z * v.z + v.w * v.w;
        unsigned short h0 = bf16_rne(v.x), h1 = bf16_rne(v.y), h2 = bf16_rne(v.z), h3 = bf16_rne(v.w);
        const size_t ob = (size_t)row * FF + i * 4;
        short4v hv = { (short)h0, (short)h1, (short)h2, (short)h3 };
        *(short4v*)(hi + ob) = hv;
        short4v lv = { (short)bf16_rne(v.x - bf16_f(h0)), (short)bf16_rne(v.y - bf16_f(h1)),
                       (short)bf16_rne(v.z - bf16_f(h2)), (short)bf16_rne(v.w - bf16_f(h3)) };
        *(short4v*)(lo + ob) = lv;
    }
    float tot = block_reduce_sum(s, red);
    if (tid == 0) nrm[row] = fmaxf(sqrtf(tot), 1e-8f);
}

// ---------------- MFMA GEMM, split-K ----------------
// C[256][4096](+epilogue->part) = A[256][4096] @ B^T, BM=256, BN=128, BK=32,
// K-chunk 512 (16 tiles). Block = 512 threads = 8 waves (4m x 2n), wave 64x64.
// grid (32, 1, 8) = 256 blocks (1/CU). No inter-block operand duplication.
// B paths (BPATH):
//  0: B given as bf16 hi/lo planes in [n][k] layout; staged via global_load_lds
//     (used for logits GEMM: B = mem planes, native layout is already [n][k]).
//  1: B given as raw fp32 [k][n] (a weight matrix); reg-staged, split to
//     bf16 hi/lo in-VALU, written to blocked LDS (fused transpose+split).
//  2: B given as bf16 plane in [k][n]; reg-staged + reblocked (zhat GEMM,
//     B = mem^T consumed from the native-layout hi plane). SPLIT=0 only.
// Blocked LDS layout per plane: byte (k8*128+n)*16 holds B[n][k8*8..k8*8+8).
template <int BPATH, int SPLIT>
__global__ __launch_bounds__(512, 2) void gemm_sk(
    const unsigned short* __restrict__ Ah, const unsigned short* __restrict__ Al,
    const void* __restrict__ B0, const void* __restrict__ B1,
    float* __restrict__ part)
{
    constexpr int PLANES = SPLIT ? 2 : 1;
    constexpr int BUFBYTES = PLANES * 8192;
    __shared__ unsigned short Bs[2 * PLANES * 4096];

    const int tid = threadIdx.x;
    const int lane = tid & 63, w = tid >> 6;
    const int wm = w >> 1, wn = w & 1;
    const int bn0 = blockIdx.x * 128;
    const int k0 = blockIdx.z * 512;
    const int l31 = lane & 31;
    const int tk8 = tid >> 7, tn = tid & 127;  // staging element (k8, n)

    // ---- BPATH 0: gll staging from [n][k] planes
    const unsigned short* bsh = nullptr; const unsigned short* bsl = nullptr;
    char* lwave = nullptr;
    if constexpr (BPATH == 0) {
        const size_t boff = (size_t)(bn0 + tn) * FF + k0 + tk8 * 8;
        bsh = (const unsigned short*)B0 + boff;
        bsl = (const unsigned short*)B1 + boff;
        lwave = (char*)Bs + (tid >> 6) * 1024;  // wave-uniform base
    }
#define STAGE(BUF_, T_)                                                       \
    {                                                                         \
        GLL16(bsh + (T_) * 32, lwave + (BUF_) * BUFBYTES + 0);                \
        GLL16(bsl + (T_) * 32, lwave + (BUF_) * BUFBYTES + 8192);             \
    }

    // ---- BPATH 1/2: reg staging bases
    const float* bf32 = nullptr; const unsigned short* bu16 = nullptr;
    if constexpr (BPATH == 1)
        bf32 = (const float*)B0 + (size_t)(k0 + tk8 * 8) * FF + bn0 + tn;
    if constexpr (BPATH == 2)
        bu16 = (const unsigned short*)B0 + (size_t)(k0 + tk8 * 8) * FF + bn0 + tn;

    float rB0, rB1, rB2, rB3, rB4, rB5, rB6, rB7;
    float sB0, sB1, sB2, sB3, sB4, sB5, sB6, sB7;
    unsigned short rU0, rU1, rU2, rU3, rU4, rU5, rU6, rU7;
    unsigned short sU0, sU1, sU2, sU3, sU4, sU5, sU6, sU7;

#define LOADB(S, T_)                                                          \
    {                                                                         \
        if constexpr (BPATH == 1) {                                           \
            const float* p_ = bf32 + (size_t)(T_) * 32 * FF;                  \
            S##B0 = p_[0 * FF]; S##B1 = p_[1 * FF];                           \
            S##B2 = p_[2 * FF]; S##B3 = p_[3 * FF];                           \
            S##B4 = p_[4 * FF]; S##B5 = p_[5 * FF];                           \
            S##B6 = p_[6 * FF]; S##B7 = p_[7 * FF];                           \
        } else if constexpr (BPATH == 2) {                                    \
            const unsigned short* p_ = bu16 + (size_t)(T_) * 32 * FF;         \
            S##U0 = p_[0 * FF]; S##U1 = p_[1 * FF];                           \
            S##U2 = p_[2 * FF]; S##U3 = p_[3 * FF];                           \
            S##U4 = p_[4 * FF]; S##U5 = p_[5 * FF];                           \
            S##U6 = p_[6 * FF]; S##U7 = p_[7 * FF];                           \
        }                                                                     \
    }

#define WRITEB(S, BUF_)                                                       \
    {                                                                         \
        if constexpr (BPATH == 1) {                                           \
            unsigned short h0_ = bf16_rne(S##B0), h1_ = bf16_rne(S##B1),      \
                           h2_ = bf16_rne(S##B2), h3_ = bf16_rne(S##B3),      \
                           h4_ = bf16_rne(S##B4), h5_ = bf16_rne(S##B5),      \
                           h6_ = bf16_rne(S##B6), h7_ = bf16_rne(S##B7);      \
            short8v hv_ = { (short)h0_, (short)h1_, (short)h2_, (short)h3_,   \
                            (short)h4_, (short)h5_, (short)h6_, (short)h7_ }; \
            *(short8v*)((char*)Bs + (BUF_) * BUFBYTES + tid * 16) = hv_;      \
            short8v lv_ = { (short)bf16_rne(S##B0 - bf16_f(h0_)),             \
                            (short)bf16_rne(S##B1 - bf16_f(h1_)),             \
                            (short)bf16_rne(S##B2 - bf16_f(h2_)),             \
                            (short)bf16_rne(S##B3 - bf16_f(h3_)),             \
                            (short)bf16_rne(S##B4 - bf16_f(h4_)),             \
                            (short)bf16_rne(S##B5 - bf16_f(h5_)),             \
                            (short)bf16_rne(S##B6 - bf16_f(h6_)),             \
                            (short)bf16_rne(S##B7 - bf16_f(h7_)) };           \
            *(short8v*)((char*)Bs + (BUF_) * BUFBYTES + 8192 + tid * 16) = lv_; \
        } else if constexpr (BPATH == 2) {                                    \
            short8v hv_ = { (short)S##U0, (short)S##U1, (short)S##U2,         \
                            (short)S##U3, (short)S##U4, (short)S##U5,         \
                            (short)S##U6, (short)S##U7 };                     \
            *(short8v*)((char*)Bs + (BUF_) * BUFBYTES + tid * 16) = hv_;      \
        }                                                                     \
    }

    // ---- B fragment reads: byte = ((kh*2 + (lane>>5))*128 + wn*64 + ns*32 + l31)*16
    const char* const fragbase =
        (const char*)Bs + (((lane >> 5) * 128) + wn * 64 + l31) * 16;
#define BFRAG(BUF_, P_, KH_, NS_)                                             \
    (*(const short8v*)(fragbase + (BUF_) * BUFBYTES + (P_) * 8192 + (KH_) * 4096 + (NS_) * 512))

    // ---- A pointers (register-direct); wave owns rows wm*64 .. wm*64+63
    const size_t arow = (size_t)(wm * 64 + l31) * FF + k0 + (lane >> 5) * 8;
    const unsigned short* a0h = Ah + arow;
    const unsigned short* a1h = a0h + (size_t)32 * FF;
    const unsigned short* a0l = SPLIT ? (Al + arow) : a0h;
    const unsigned short* a1l = a0l + (size_t)32 * FF;

    short8v cA_0h0, cA_0h1, cA_1h0, cA_1h1, cA_0l0, cA_0l1, cA_1l0, cA_1l1;
    short8v nA_0h0, nA_0h1, nA_1h0, nA_1h1, nA_0l0, nA_0l1, nA_1l0, nA_1l1;

#define LOADA(SET, T_)                                                        \
    {                                                                         \
        const int o_ = (T_) * 32;                                             \
        SET##_0h0 = *(const short8v*)(a0h + o_);                              \
        SET##_0h1 = *(const short8v*)(a0h + o_ + 16);                         \
        SET##_1h0 = *(const short8v*)(a1h + o_);                              \
        SET##_1h1 = *(const short8v*)(a1h + o_ + 16);                         \
        if constexpr (SPLIT) {                                                \
            SET##_0l0 = *(const short8v*)(a0l + o_);                          \
            SET##_0l1 = *(const short8v*)(a0l + o_ + 16);                     \
            SET##_1l0 = *(const short8v*)(a1l + o_);                          \
            SET##_1l1 = *(const short8v*)(a1l + o_ + 16);                     \
        }                                                                     \
    }

    f32x16 acc00 = 0.0f, acc01 = 0.0f, acc10 = 0.0f, acc11 = 0.0f;

#define MFMA(A_, B_, C_) C_ = __builtin_amdgcn_mfma_f32_32x32x16_bf16(A_, B_, C_, 0, 0, 0)
#define MMKS(SET, BUF_, KH_)                                                  \
    {                                                                         \
        short8v bh0 = BFRAG(BUF_, 0, KH_, 0);                                 \
        short8v bh1 = BFRAG(BUF_, 0, KH_, 1);                                 \
        MFMA(SET##_0h##KH_, bh0, acc00); MFMA(SET##_0h##KH_, bh1, acc01);     \
        MFMA(SET##_1h##KH_, bh0, acc10); MFMA(SET##_1h##KH_, bh1, acc11);     \
        if constexpr (SPLIT) {                                                \
            short8v bl0 = BFRAG(BUF_, 1, KH_, 0);                             \
            short8v bl1 = BFRAG(BUF_, 1, KH_, 1);                             \
            MFMA(SET##_0h##KH_, bl0, acc00); MFMA(SET##_0h##KH_, bl1, acc01); \
            MFMA(SET##_1h##KH_, bl0, acc10); MFMA(SET##_1h##KH_, bl1, acc11); \
            MFMA(SET##_0l##KH_, bh0, acc00); MFMA(SET##_0l##KH_, bh1, acc01); \
            MFMA(SET##_1l##KH_, bh0, acc10); MFMA(SET##_1l##KH_, bh1, acc11); \
        }                                                                     \
    }

    if constexpr (BPATH == 0) {
        // gll 2-buffer loop (R4 pattern)
        STAGE(0, 0)
        LOADA(cA, 0)
        __syncthreads();
#pragma unroll
        for (int tp = 0; tp < 8; ++tp) {
            const int t = tp * 2;
            STAGE(1, t + 1)
            LOADA(nA, t + 1)
            __builtin_amdgcn_s_setprio(1);
            MMKS(cA, 0, 0)
            MMKS(cA, 0, 1)
            __builtin_amdgcn_s_setprio(0);
            __syncthreads();
            if (tp < 7) { STAGE(0, t + 2) LOADA(cA, t + 2) }
            __builtin_amdgcn_s_setprio(1);
            MMKS(nA, 1, 0)
            MMKS(nA, 1, 1)
            __builtin_amdgcn_s_setprio(0);
            __syncthreads();
        }
    } else {
        // reg-stage loop: issue loads early, MFMA, write blocked, barrier.
        LOADB(r, 0)
        LOADA(cA, 0)
        WRITEB(r, 0)
        __syncthreads();
#pragma unroll
        for (int tp = 0; tp < 8; ++tp) {
            const int t = tp * 2;
            LOADB(s, t + 1)
            LOADA(nA, t + 1)
            __builtin_amdgcn_s_setprio(1);
            MMKS(cA, 0, 0)
            MMKS(cA, 0, 1)
            __builtin_amdgcn_s_setprio(0);
            WRITEB(s, 1)
            __syncthreads();
            if (tp < 7) { LOADB(r, t + 2) LOADA(cA, t + 2) }
            __builtin_amdgcn_s_setprio(1);
            MMKS(nA, 1, 0)
            MMKS(nA, 1, 1)
            __builtin_amdgcn_s_setprio(0);
            if (tp < 7) { WRITEB(r, 0) }
            __syncthreads();
        }
    }
#undef STAGE
#undef LOADB
#undef WRITEB
#undef BFRAG
#undef LOADA
#undef MFMA
#undef MMKS

    float* pp = part + (size_t)blockIdx.z * (MB * FF);
    const int rbase = wm * 64 + 4 * (lane >> 5);
    const int c0 = bn0 + wn * 64 + l31;
#pragma unroll
    for (int r = 0; r < 16; ++r) {
        const int row0 = rbase + (r & 3) + 8 * (r >> 2);
        float* rp0 = pp + (size_t)row0 * FF + c0;
        rp0[0]  = acc00[r];
        rp0[32] = acc01[r];
        float* rp1 = rp0 + (size_t)32 * FF;
        rp1[0]  = acc10[r];
        rp1[32] = acc11[r];
    }
}

// ---------------- split-K reduce + epilogue ----------------
// MODE 0: +bias -> hi/lo planes.  MODE 1: +bias -> hi/lo + f32.
// MODE 2: /(zn*mn) -> f32.        MODE 3: plain -> f32.
template <int MODE>
__global__ __launch_bounds__(256) void reduce_k(
    const float* __restrict__ part, const float* __restrict__ bias,
    const float* __restrict__ zn, const float* __restrict__ mn,
    unsigned short* __restrict__ hi, unsigned short* __restrict__ lo,
    float* __restrict__ fout)
{
    const size_t idx4 = (size_t)blockIdx.x * 256 + threadIdx.x;
    const size_t base = idx4 * 4;
    float s0 = 0.f, s1 = 0.f, s2 = 0.f, s3 = 0.f;
#pragma unroll
    for (int c = 0; c < 8; ++c) {
        const float4 p = *(const float4*)(part + (size_t)c * (MB * FF) + base);
        s0 += p.x; s1 += p.y; s2 += p.z; s3 += p.w;
    }
    const int col = (int)(base & 4095);
    const int row = (int)(base >> 12);
    if constexpr (MODE == 0 || MODE == 1) {
        s0 += bias[col]; s1 += bias[col + 1]; s2 += bias[col + 2]; s3 += bias[col + 3];
        unsigned short h0 = bf16_rne(s0), h1 = bf16_rne(s1), h2 = bf16_rne(s2), h3 = bf16_rne(s3);
        short4v hv = { (short)h0, (short)h1, (short)h2, (short)h3 };
        *(short4v*)(hi + base) = hv;
        short4v lv = { (short)bf16_rne(s0 - bf16_f(h0)), (short)bf16_rne(s1 - bf16_f(h1)),
                       (short)bf16_rne(s2 - bf16_f(h2)), (short)bf16_rne(s3 - bf16_f(h3)) };
        *(short4v*)(lo + base) = lv;
        if constexpr (MODE == 1) {
            float4 o = { s0, s1, s2, s3 };
            *(float4*)(fout + base) = o;
        }
    } else if constexpr (MODE == 2) {
        const float zr = zn[row];
        float4 o = { s0 / (zr * mn[col]), s1 / (zr * mn[col + 1]),
                     s2 / (zr * mn[col + 2]), s3 / (zr * mn[col + 3]) };
        *(float4*)(fout + base) = o;
    } else {
        float4 o = { s0, s1, s2, s3 };
        *(float4*)(fout + base) = o;
    }
}

// ---------------- softmax + shrinkage + renorm + entropy ----------------
__global__ __launch_bounds__(256) void softmax_shrink_kernel(
    const float* __restrict__ logits, unsigned short* __restrict__ w_hi,
    float* __restrict__ rowent)
{
    constexpr float THRESH = 1.0f / 4096.0f;
    constexpr float EPS = 1e-12f;
    __shared__ float srow[4096];
    __shared__ float red[256];
    const int row = blockIdx.x, tid = threadIdx.x;
    const float4* p = (const float4*)(logits + (size_t)row * FF);
    for (int i = tid; i < FF / 4; i += 256) ((float4*)srow)[i] = p[i];
    __syncthreads();

    float m = -INFINITY;
    for (int i = tid; i < FF; i += 256) m = fmaxf(m, srow[i]);
    m = block_reduce_max(m, red);

    float s = 0.f;
    for (int i = tid; i < FF; i += 256) {
        float e = expf(srow[i] - m);
        srow[i] = e; s += e;
    }
    s = block_reduce_sum(s, red);
    const float inv = 1.0f / s;

    float s2 = 0.f;
    for (int i = tid; i < FF; i += 256) {
        float w = srow[i] * inv;
        float d = w - THRESH;
        float w2 = fmaxf(d, 0.f) * w / (fabsf(d) + EPS);
        srow[i] = w2; s2 += w2;
    }
    __syncthreads();
    s2 = block_reduce_sum(s2, red);
    const float inv2 = 1.0f / fmaxf(s2, EPS);

    float ent = 0.f;
    for (int i = tid; i < FF; i += 256) {
        float w3 = srow[i] * inv2;
        w_hi[(size_t)row * FF + i] = bf16_rne(w3);
        ent -= w3 * logf(w3 + EPS);
    }
    ent = block_reduce_sum(ent, red);
    if (tid == 0) rowent[row] = ent;
}

__global__ __launch_bounds__(256) void loss_kernel(
    const float* __restrict__ rowent, float* __restrict__ out)
{
    __shared__ float red[256];
    const int tid = threadIdx.x;
    float tot = block_reduce_sum(rowent[tid], red);
    if (tid == 0) out[0] = (tot / 256.0f) * 0.0002f;
}

extern "C" void kernel_launch(void* const* d_in, const int* in_sizes, int n_in,
                              void* d_out, int out_size, void* d_ws, size_t ws_size,
                              hipStream_t stream)
{
    // inputs: x, memory, Wq, bq, Wk, bk, Wv, bv, Wo, bo
    const float* x   = (const float*)d_in[0];
    const float* mem = (const float*)d_in[1];
    const float* Wv  = (const float*)d_in[6];
    const float* bv  = (const float*)d_in[7];
    const float* Wo  = (const float*)d_in[8];
    const float* bo  = (const float*)d_in[9];
    float* out = (float*)d_out;

    char* ws = (char*)d_ws;
    unsigned short* M_hi  = (unsigned short*)(ws + 67108864ull);   // 32 MB  (mem split, native)
    unsigned short* M_lo  = (unsigned short*)(ws + 100663296ull);  // 32 MB
    float*          part  = (float*)(ws + 134217728ull);           // 32 MB  (8 split-K partials)
    unsigned short* x_hi  = (unsigned short*)(ws + 167772160ull);  // 2 MB
    unsigned short* x_lo  = (unsigned short*)(ws + 169869312ull);
    unsigned short* v_hi  = (unsigned short*)(ws + 171966464ull);
    unsigned short* v_lo  = (unsigned short*)(ws + 174063616ull);
    unsigned short* o_hi  = (unsigned short*)(ws + 176160768ull);
    unsigned short* o_lo  = (unsigned short*)(ws + 178257920ull);
    float*          o_f32 = (float*)(ws + 180355072ull);           // 4 MB
    float*          logit = (float*)(ws + 184549376ull);           // 4 MB
    unsigned short* w_hi  = (unsigned short*)(ws + 188743680ull);  // 2 MB
    float*          zn    = (float*)(ws + 190840832ull);
    float*          mn    = zn + MB;
    float*          rowe  = mn + FF;

    const dim3 blk(256);
    const dim3 blkG(512);
    const dim3 gG(32, 1, 8);      // gemm: N/128, M/256, split-K 8
    const int gR = (MB * FF) / (4 * 256);  // 1024

    // prep
    split_plain<<<gR, blk, 0, stream>>>(x, x_hi, x_lo);
    split_norm_mem<<<FF, blk, 0, stream>>>(mem, M_hi, M_lo, mn);

    // v = z @ Wv + bv   (B = raw fp32 Wv, transpose+split fused in-GEMM)
    gemm_sk<1, 1><<<gG, blkG, 0, stream>>>(x_hi, x_lo, Wv, nullptr, part);
    reduce_k<0><<<gR, blk, 0, stream>>>(part, bv, nullptr, nullptr, v_hi, v_lo, nullptr);

    // o = v @ Wo + bo
    gemm_sk<1, 1><<<gG, blkG, 0, stream>>>(v_hi, v_lo, Wo, nullptr, part);
    reduce_k<1><<<gR, blk, 0, stream>>>(part, bo, nullptr, nullptr, o_hi, o_lo, o_f32);

    // logits = (o @ mem^T) / (zn x mn)   [mem native rows ARE the B^T layout]
    rownorm_kernel<<<MB, blk, 0, stream>>>(o_f32, zn, FF);
    gemm_sk<0, 1><<<gG, blkG, 0, stream>>>(o_hi, o_lo, M_hi, M_lo, part);
    reduce_k<2><<<gR, blk, 0, stream>>>(part, nullptr, zn, mn, nullptr, nullptr, logit);

    // softmax/shrink/renorm/entropy -> w (bf16)
    softmax_shrink_kernel<<<MB, blk, 0, stream>>>(logit, w_hi, rowe);

    // z_hat = w @ mem   (plain bf16; mem^T consumed from native hi plane)
    gemm_sk<2, 0><<<gG, blkG, 0, stream>>>(w_hi, nullptr, M_hi, nullptr, part);
    reduce_k<3><<<gR, blk, 0, stream>>>(part, nullptr, nullptr, nullptr, nullptr, nullptr, out);

    loss_kernel<<<1, blk, 0, stream>>>(rowe, out + (size_t)MB * FF);
}